// Round 17
// baseline (26140.771 us; speedup 1.0000x reference)
//
#include <hip/hip_runtime.h>

#define Bn 128
#define Tn 1024
#define INn 256
#define Hn 512
#define NB 256   // persistent blocks (1 per CU), 1024 threads each

typedef short bf16x8 __attribute__((ext_vector_type(8)));
typedef float f32x4 __attribute__((ext_vector_type(4)));

// ---- ws layout (bytes) ----
#define WPK_OFF  0u           // bf16 packed weights 23068672 B
#define BIAS_OFF 23068672u    // f32[3][2048]
#define H_OFF    23093248u    // f32 h[3][2][128][512], MALL/sys-coherent
#define H3F_OFF  24666112u    // f32[128][512]
#define BAR_OFF  24928256u    // 8KB barrier

// packed-weight bases (bf16 elems); per-G slab: l0=24576, l1/l2=32768 elems
#define L0B 0u
#define L1B 3145728u
#define L2B 7340032u

__device__ __forceinline__ float sigm(float x) { return 1.0f / (1.0f + __expf(-x)); }
__device__ __forceinline__ unsigned short bf_hi(float x) {
  unsigned u = __builtin_bit_cast(unsigned, x);
  return (unsigned short)(u >> 16);
}
__device__ __forceinline__ float bf_f(unsigned short h) {
  unsigned u = ((unsigned)h) << 16;
  return __builtin_bit_cast(float, u);
}

// Pack fp32 weights -> per-(layer, 16-col group G) slabs in MFMA fragment
// order (r13-proven layout). slab = [NCH][64][8] hi then same-size lo.
// col n = lane&15 -> gate g=n>>2, jl=n&3 -> row r = g*512 + G*4 + jl;
// k0 = kc*32 + (lane>>4)*8 over concat [x ; h].
__global__ void pack_weights(const float* __restrict__ wih1, const float* __restrict__ whh1,
                             const float* __restrict__ wih2, const float* __restrict__ whh2,
                             const float* __restrict__ wih3, const float* __restrict__ whh3,
                             unsigned short* __restrict__ wpk) {
  int gid = blockIdx.x * 256 + threadIdx.x;
  int rem, NCH, kih; size_t base, slab; const float *wih, *whh;
  if (gid < 196608)      { rem = gid;          base = L0B; slab = 24576; NCH = 24; kih = 256; wih = wih1; whh = whh1; }
  else if (gid < 458752) { rem = gid - 196608; base = L1B; slab = 32768; NCH = 32; kih = 512; wih = wih2; whh = whh2; }
  else if (gid < 720896) { rem = gid - 458752; base = L2B; slab = 32768; NCH = 32; kih = 512; wih = wih3; whh = whh3; }
  else return;
  const int lane = rem & 63; rem >>= 6;
  const int kc = rem % NCH; rem /= NCH;
  const int G = rem;                      // 0..127
  const int n = lane & 15;
  const int g = n >> 2, jl = n & 3;
  const int r = g * 512 + G * 4 + jl;
  const int k0 = kc * 32 + (lane >> 4) * 8;
  const float* src = (k0 < kih) ? (wih + (size_t)r * kih + k0)
                                : (whh + (size_t)r * 512 + (k0 - kih));
  const size_t dhi = base + (size_t)G * slab + (size_t)kc * 512 + lane * 8;
  const size_t dlo = dhi + (size_t)NCH * 512;
#pragma unroll
  for (int e = 0; e < 8; ++e) {
    float w = src[e];
    unsigned short h = bf_hi(w);
    wpk[dhi + e] = h;
    wpk[dlo + e] = bf_hi(w - bf_f(h));
  }
}

__global__ void pack_bias(const float* __restrict__ bi1, const float* __restrict__ bh1,
                          const float* __restrict__ bi2, const float* __restrict__ bh2,
                          const float* __restrict__ bi3, const float* __restrict__ bh3,
                          float* __restrict__ bias) {
  int gid = blockIdx.x * 256 + threadIdx.x;
  if (gid >= 6144) return;
  int l = gid >> 11, r = gid & 2047;
  const float* bi = (l == 0) ? bi1 : (l == 1) ? bi2 : bi3;
  const float* bh = (l == 0) ? bh1 : (l == 1) ? bh2 : bh3;
  bias[gid] = bi[r] + bh[r];
}

// Grid barrier, ALL RELAXED (r9-proven). Counter-sharding by bid&7.
__device__ __forceinline__ void gridbar(unsigned* bar, unsigned idx, int shard) {
  __syncthreads();
  if (threadIdx.x == 0) {
    asm volatile("" ::: "memory");
    unsigned o = __hip_atomic_fetch_add(bar + shard * 32, 1u, __ATOMIC_RELAXED, __HIP_MEMORY_SCOPE_AGENT);
    if (o == idx * 32u - 1u) {
      unsigned r = __hip_atomic_fetch_add(bar + 256, 1u, __ATOMIC_RELAXED, __HIP_MEMORY_SCOPE_AGENT);
      if (r == idx * 8u - 1u)
        __hip_atomic_store(bar + 288, idx, __ATOMIC_RELAXED, __HIP_MEMORY_SCOPE_AGENT);
    }
    while (__hip_atomic_load(bar + 288, __ATOMIC_RELAXED, __HIP_MEMORY_SCOPE_AGENT) < idx)
      __builtin_amdgcn_s_sleep(1);
    asm volatile("" ::: "memory");
  }
  __syncthreads();
}

// Persistent fused LSTM: 256 blocks x 1024 threads (16 waves = 4/SIMD).
// Block = (b-tile 16: bt=bid>>5, j-tile 16: jt=bid&31); bid%8 fixes jt%8 ->
// 2.88 MB weights/XCD (L2-resident).
// r17 changes vs r16: (1) B-HI WEIGHTS REGISTER-RESIDENT -- each wave loads
// its (6+8+8) kc x 16B hi-slice ONCE before the phase loop (88 VGPRs,
// static-indexed full-unroll arrays); only wlo streams from L2 (halves
// per-phase L2 weight traffic). (2) pre stride 65->68 (68 mod 32 = 4):
// the 4-row x 16-col accumulator write is exactly 2-way per bank (free).
__global__ __launch_bounds__(1024) void lstm_persist(
    const float* __restrict__ embed,
    const unsigned short* __restrict__ wpk,
    const float* __restrict__ bias,
    float* __restrict__ hsys,
    float* __restrict__ h3f,
    unsigned* __restrict__ bar)
{
  const int bid = blockIdx.x;
  const int shard = bid & 7;
  const int jt = bid & 31;           // j-tile 16
  const int bt = bid >> 5;           // b-tile 16
  const int tid = (int)threadIdx.x;
  const int lane = tid & 63;
  const int w = tid >> 6;            // 0..15
  const int nsub = w & 3, kq = w >> 2;

  __shared__ short als[2][56][520];      // 116480 B, fragment-major + pad
  __shared__ float pre[2][4][16][68];    // 34816 B, stride 68 -> 2-way banks
  __shared__ float sbias[3][64];         // 768 B

  if (tid < 192) {
    const int l = tid >> 6, c = tid & 63;
    const int n = c & 15, g = n >> 2;
    sbias[l][c] = bias[l * 2048 + g * 512 + jt * 16 + (c >> 4) * 4 + (n & 3)];
  }
  // zero h (sys, deterministic per launch)
  unsigned long long* hz = (unsigned long long*)hsys;
  for (int i = bid * 1024 + tid; i < 196608; i += NB * 1024)
    __hip_atomic_store(hz + i, 0ull, __ATOMIC_RELAXED, __HIP_MEMORY_SCOPE_SYSTEM);

  // ---- register-resident B-hi: load once (static indexing, full unroll) ----
  const int G = jt * 4 + nsub;
  bf16x8 bh0[6], bh1[8], bh2[8];
  {
    const unsigned short* w0 = wpk + L0B + (size_t)G * 24576 + (size_t)lane * 8;
#pragma unroll
    for (int i = 0; i < 6; ++i)
      bh0[i] = *reinterpret_cast<const bf16x8*>(w0 + (size_t)(kq * 6 + i) * 512);
    const unsigned short* w1 = wpk + L1B + (size_t)G * 32768 + (size_t)lane * 8;
#pragma unroll
    for (int i = 0; i < 8; ++i)
      bh1[i] = *reinterpret_cast<const bf16x8*>(w1 + (size_t)(kq * 8 + i) * 512);
    const unsigned short* w2 = wpk + L2B + (size_t)G * 32768 + (size_t)lane * 8;
#pragma unroll
    for (int i = 0; i < 8; ++i)
      bh2[i] = *reinterpret_cast<const bf16x8*>(w2 + (size_t)(kq * 8 + i) * 512);
  }

  float c0 = 0.f, c1 = 0.f, c2 = 0.f;   // cell state (bt*16+(tid>>4), jt*16+(tid&15)), tid<256
  unsigned bidx = 1;
  gridbar(bar, bidx++, shard);

  const unsigned long long* hs_u = (const unsigned long long*)hsys;

  // per-layer MFMA pass: A from fragment-major LDS, B-hi from REGISTERS,
  // B-lo streamed from L2.
#define MFMA_LAYER(BH, NCHV, Q4V, WBASE, SLABV, LBASE, PL)                              \
  do {                                                                                   \
    const unsigned short* wl_ = wpk + (WBASE) + (size_t)(NCHV) * 512 +                   \
                                (size_t)G * (SLABV) + (size_t)lane * 8;                  \
    f32x4 accE = {0.f,0.f,0.f,0.f}, accO = {0.f,0.f,0.f,0.f};                            \
    _Pragma("unroll")                                                                    \
    for (int i = 0; i < (Q4V); ++i) {                                                    \
      const int kc = kq * (Q4V) + i;                                                     \
      const int ch = (LBASE) + kc;                                                       \
      const bf16x8 aH = *reinterpret_cast<const bf16x8*>(&als[0][ch][lane * 8]);         \
      const bf16x8 aL = *reinterpret_cast<const bf16x8*>(&als[1][ch][lane * 8]);         \
      const bf16x8 bH = (BH)[i];                                                         \
      const bf16x8 bL = *reinterpret_cast<const bf16x8*>(wl_ + (size_t)kc * 512);        \
      if (i & 1) {                                                                       \
        accO = __builtin_amdgcn_mfma_f32_16x16x32_bf16(aH, bH, accO, 0, 0, 0);           \
        accO = __builtin_amdgcn_mfma_f32_16x16x32_bf16(aL, bH, accO, 0, 0, 0);           \
        accO = __builtin_amdgcn_mfma_f32_16x16x32_bf16(aH, bL, accO, 0, 0, 0);           \
        accO = __builtin_amdgcn_mfma_f32_16x16x32_bf16(aL, bL, accO, 0, 0, 0);           \
      } else {                                                                           \
        accE = __builtin_amdgcn_mfma_f32_16x16x32_bf16(aH, bH, accE, 0, 0, 0);           \
        accE = __builtin_amdgcn_mfma_f32_16x16x32_bf16(aL, bH, accE, 0, 0, 0);           \
        accE = __builtin_amdgcn_mfma_f32_16x16x32_bf16(aH, bL, accE, 0, 0, 0);           \
        accE = __builtin_amdgcn_mfma_f32_16x16x32_bf16(aL, bL, accE, 0, 0, 0);           \
      }                                                                                  \
    }                                                                                    \
    const int prow = (lane >> 4) << 2;                                                   \
    const int pc = lane & 15;                                                            \
    _Pragma("unroll")                                                                    \
    for (int r = 0; r < 4; ++r)                                                          \
      pre[PL][kq][prow + r][nsub * 16 + pc] = accE[r] + accO[r];                         \
  } while (0)

  // cell update for one layer (tid<256): b=tid>>4, jl=tid&15
  auto cell_layer = [&](int l, int pl, int wp, int t, float& c) {
    const int b = tid >> 4, jl = tid & 15;
    float gv[4];
#pragma unroll
    for (int gi = 0; gi < 4; ++gi) {
      const int cc = (jl >> 2) * 16 + gi * 4 + (jl & 3);
      gv[gi] = sbias[l][cc] + pre[pl][0][b][cc] + pre[pl][1][b][cc]
             + pre[pl][2][b][cc] + pre[pl][3][b][cc];
    }
    const float ig = sigm(gv[0]), fg = sigm(gv[1]), gg = tanhf(gv[2]), og = sigm(gv[3]);
    c = fg * c + ig * gg;
    const float hv = og * tanhf(c);
    __hip_atomic_store((unsigned*)hsys +
        ((size_t)(l * 2 + wp) * 65536 + (size_t)(bt * 16 + b) * 512 + jt * 16 + jl),
        __builtin_bit_cast(unsigned, hv), __ATOMIC_RELAXED, __HIP_MEMORY_SCOPE_SYSTEM);
    if (l == 2 && t == 1022)
      h3f[(size_t)(bt * 16 + b) * 512 + jt * 16 + jl] = hv;
  };

  for (int p = 0; p <= 1024; ++p) {
    const int rp = (p + 1) & 1, wp = p & 1;
    const bool a0 = (p <= 1022), a1 = (p >= 1) && (p <= 1023), a2 = (p >= 2);

    // ---- deduped stage, ch-major: sub = consuming lane; writes contiguous ----
    for (int u = tid; u < 3584; u += 1024) {
      float xs[8];
      int ch, sub;
      if (u < 512) {                       // embed: chunks 0-7
        if (p > 1022) continue;
        ch = u >> 6; sub = u & 63;
        const int row = sub & 15, kg = sub >> 4;
        const int k0 = ch * 32 + kg * 8;
        const float* s = embed + ((size_t)(bt * 16 + row) * Tn + p) * INn + k0;
        const f32x4 x0 = __builtin_nontemporal_load(reinterpret_cast<const f32x4*>(s));
        const f32x4 x1 = __builtin_nontemporal_load(reinterpret_cast<const f32x4*>(s) + 1);
        xs[0]=x0.x; xs[1]=x0.y; xs[2]=x0.z; xs[3]=x0.w;
        xs[4]=x1.x; xs[5]=x1.y; xs[6]=x1.z; xs[7]=x1.w;
      } else {                             // h_li: chunks 8..55
        const int v = u - 512;
        const int chh = v >> 6;            // 0..47
        ch = 8 + chh; sub = v & 63;
        const int li = chh >> 4;           // 0..2
        const int row = sub & 15, kg = sub >> 4;
        const int kcol = (chh & 15) * 32 + kg * 8;   // within li's 512
        const unsigned long long* sp = hs_u +
            ((size_t)(li * 2 + rp) * 32768 + (size_t)(bt * 16 + row) * 256 + (kcol >> 1));
#pragma unroll
        for (int q = 0; q < 4; ++q) {
          unsigned long long vv = __hip_atomic_load(sp + q, __ATOMIC_RELAXED, __HIP_MEMORY_SCOPE_SYSTEM);
          xs[2*q]   = __builtin_bit_cast(float, (unsigned)(vv & 0xffffffffu));
          xs[2*q+1] = __builtin_bit_cast(float, (unsigned)(vv >> 32));
        }
      }
      bf16x8 vh, vl;
#pragma unroll
      for (int e = 0; e < 8; ++e) {
        unsigned short h1 = bf_hi(xs[e]);
        vh[e] = (short)h1;
        vl[e] = (short)bf_hi(xs[e] - bf_f(h1));
      }
      *reinterpret_cast<bf16x8*>(&als[0][ch][sub * 8]) = vh;
      *reinterpret_cast<bf16x8*>(&als[1][ch][sub * 8]) = vl;
    }
    __syncthreads();

    // ---- mfma l0 -> pre[0], l1 -> pre[1] ----
    if (a0) MFMA_LAYER(bh0, 24, 6, L0B, 24576, 0, 0);
    if (a1) MFMA_LAYER(bh1, 32, 8, L1B, 32768, 8, 1);
    __syncthreads();
    if (tid < 256) {
      if (a0) cell_layer(0, 0, wp, p, c0);
      if (a1) cell_layer(1, 1, wp, p - 1, c1);
    }
    __syncthreads();

    // ---- mfma l2 -> pre[0] (cells above already consumed pre[0]) ----
    if (a2) MFMA_LAYER(bh2, 32, 8, L2B, 32768, 24, 0);
    __syncthreads();
    if (tid < 256 && a2) cell_layer(2, 0, wp, p - 2, c2);

    gridbar(bar, bidx++, shard);
  }
}

// FC epilogue: out2[b][o] = h3_final[b,:] . fc_w[o,:] + fc_b[o]
__global__ void fc_kernel(const float* __restrict__ h3f, const float* __restrict__ fcw,
                          const float* __restrict__ fcb, float* __restrict__ out) {
  const int gid = blockIdx.x * 256 + (int)threadIdx.x;
  if (gid >= Bn * INn) return;
  const int b = gid >> 8, o = gid & 255;
  const float* hr = h3f + (size_t)b * Hn;
  const float* wr = fcw + (size_t)o * Hn;
  float acc = fcb[o];
#pragma unroll 4
  for (int k = 0; k < Hn; k += 4) {
    const float4 hv = *reinterpret_cast<const float4*>(hr + k);
    const float4 wv = *reinterpret_cast<const float4*>(wr + k);
    acc = fmaf(hv.x, wv.x, acc); acc = fmaf(hv.y, wv.y, acc);
    acc = fmaf(hv.z, wv.z, acc); acc = fmaf(hv.w, wv.w, acc);
  }
  out[(size_t)Bn * Tn * INn + gid] = acc;
}

extern "C" void kernel_launch(void* const* d_in, const int* in_sizes, int n_in,
                              void* d_out, int out_size, void* d_ws, size_t ws_size,
                              hipStream_t stream) {
  const float* embed = (const float*)d_in[0];
  const float* wih1  = (const float*)d_in[1];
  const float* whh1  = (const float*)d_in[2];
  const float* bih1  = (const float*)d_in[3];
  const float* bhh1  = (const float*)d_in[4];
  const float* wih2  = (const float*)d_in[5];
  const float* whh2  = (const float*)d_in[6];
  const float* bih2  = (const float*)d_in[7];
  const float* bhh2  = (const float*)d_in[8];
  const float* wih3  = (const float*)d_in[9];
  const float* whh3  = (const float*)d_in[10];
  const float* bih3  = (const float*)d_in[11];
  const float* bhh3  = (const float*)d_in[12];
  const float* fcw   = (const float*)d_in[13];
  const float* fcb   = (const float*)d_in[14];
  float* outp = (float*)d_out;

  char* ws = (char*)d_ws;
  unsigned short* wpk = (unsigned short*)(ws + WPK_OFF);
  float* bias         = (float*)(ws + BIAS_OFF);
  float* hsys         = (float*)(ws + H_OFF);
  float* h3f          = (float*)(ws + H3F_OFF);
  unsigned* bar       = (unsigned*)(ws + BAR_OFF);

  // Output 0: embed passthrough (128 MB d2d)
  hipMemcpyAsync(d_out, d_in[0], (size_t)Bn * Tn * INn * sizeof(float),
                 hipMemcpyDeviceToDevice, stream);
  hipMemsetAsync(bar, 0, 8192, stream);

  pack_weights<<<2816, 256, 0, stream>>>(wih1, whh1, wih2, whh2, wih3, whh3, wpk);
  pack_bias<<<24, 256, 0, stream>>>(bih1, bhh1, bih2, bhh2, bih3, bhh3, bias);

  void* args[] = { (void*)&embed, (void*)&wpk, (void*)&bias,
                   (void*)&hsys, (void*)&h3f, (void*)&bar };
  dim3 grid(NB), block(1024);
  hipLaunchCooperativeKernel((const void*)lstm_persist, grid, block, args, 0, stream);

  fc_kernel<<<128, 256, 0, stream>>>(h3f, fcw, fcb, outp);
}

// Round 18
// 25092.343 us; speedup vs baseline: 1.0418x; 1.0418x over previous
//
#include <hip/hip_runtime.h>

#define Bn 128
#define Tn 1024
#define INn 256
#define Hn 512
#define NB 256   // persistent blocks (1 per CU), 1024 threads each

typedef short bf16x8 __attribute__((ext_vector_type(8)));
typedef float f32x4 __attribute__((ext_vector_type(4)));

// ---- ws layout (bytes) ----
#define WPK_OFF  0u           // bf16 packed weights 23068672 B
#define BIAS_OFF 23068672u    // f32[3][2048]
#define H_OFF    23093248u    // f32 h[3][2][128][512], MALL/sys-coherent
#define H3F_OFF  24666112u    // f32[128][512]
#define BAR_OFF  24928256u    // 8KB barrier

// packed-weight bases (bf16 elems); per-G slab: l0=24576, l1/l2=32768 elems
#define L0B 0u
#define L1B 3145728u
#define L2B 7340032u

__device__ __forceinline__ float sigm(float x) { return 1.0f / (1.0f + __expf(-x)); }
__device__ __forceinline__ unsigned short bf_hi(float x) {
  unsigned u = __builtin_bit_cast(unsigned, x);
  return (unsigned short)(u >> 16);
}
__device__ __forceinline__ float bf_f(unsigned short h) {
  unsigned u = ((unsigned)h) << 16;
  return __builtin_bit_cast(float, u);
}

// Pack fp32 weights -> per-(layer, 16-col group G) slabs in MFMA fragment
// order (r13-proven layout). slab = [NCH][64][8] hi then same-size lo.
// col n = lane&15 -> gate g=n>>2, jl=n&3 -> row r = g*512 + G*4 + jl;
// k0 = kc*32 + (lane>>4)*8 over concat [x ; h].
__global__ void pack_weights(const float* __restrict__ wih1, const float* __restrict__ whh1,
                             const float* __restrict__ wih2, const float* __restrict__ whh2,
                             const float* __restrict__ wih3, const float* __restrict__ whh3,
                             unsigned short* __restrict__ wpk) {
  int gid = blockIdx.x * 256 + threadIdx.x;
  int rem, NCH, kih; size_t base, slab; const float *wih, *whh;
  if (gid < 196608)      { rem = gid;          base = L0B; slab = 24576; NCH = 24; kih = 256; wih = wih1; whh = whh1; }
  else if (gid < 458752) { rem = gid - 196608; base = L1B; slab = 32768; NCH = 32; kih = 512; wih = wih2; whh = whh2; }
  else if (gid < 720896) { rem = gid - 458752; base = L2B; slab = 32768; NCH = 32; kih = 512; wih = wih3; whh = whh3; }
  else return;
  const int lane = rem & 63; rem >>= 6;
  const int kc = rem % NCH; rem /= NCH;
  const int G = rem;                      // 0..127
  const int n = lane & 15;
  const int g = n >> 2, jl = n & 3;
  const int r = g * 512 + G * 4 + jl;
  const int k0 = kc * 32 + (lane >> 4) * 8;
  const float* src = (k0 < kih) ? (wih + (size_t)r * kih + k0)
                                : (whh + (size_t)r * 512 + (k0 - kih));
  const size_t dhi = base + (size_t)G * slab + (size_t)kc * 512 + lane * 8;
  const size_t dlo = dhi + (size_t)NCH * 512;
#pragma unroll
  for (int e = 0; e < 8; ++e) {
    float w = src[e];
    unsigned short h = bf_hi(w);
    wpk[dhi + e] = h;
    wpk[dlo + e] = bf_hi(w - bf_f(h));
  }
}

__global__ void pack_bias(const float* __restrict__ bi1, const float* __restrict__ bh1,
                          const float* __restrict__ bi2, const float* __restrict__ bh2,
                          const float* __restrict__ bi3, const float* __restrict__ bh3,
                          float* __restrict__ bias) {
  int gid = blockIdx.x * 256 + threadIdx.x;
  if (gid >= 6144) return;
  int l = gid >> 11, r = gid & 2047;
  const float* bi = (l == 0) ? bi1 : (l == 1) ? bi2 : bi3;
  const float* bh = (l == 0) ? bh1 : (l == 1) ? bh2 : bh3;
  bias[gid] = bi[r] + bh[r];
}

// Grid barrier, ALL RELAXED (r9-proven). Counter-sharding by bid&7.
__device__ __forceinline__ void gridbar(unsigned* bar, unsigned idx, int shard) {
  __syncthreads();
  if (threadIdx.x == 0) {
    asm volatile("" ::: "memory");
    unsigned o = __hip_atomic_fetch_add(bar + shard * 32, 1u, __ATOMIC_RELAXED, __HIP_MEMORY_SCOPE_AGENT);
    if (o == idx * 32u - 1u) {
      unsigned r = __hip_atomic_fetch_add(bar + 256, 1u, __ATOMIC_RELAXED, __HIP_MEMORY_SCOPE_AGENT);
      if (r == idx * 8u - 1u)
        __hip_atomic_store(bar + 288, idx, __ATOMIC_RELAXED, __HIP_MEMORY_SCOPE_AGENT);
    }
    while (__hip_atomic_load(bar + 288, __ATOMIC_RELAXED, __HIP_MEMORY_SCOPE_AGENT) < idx)
      __builtin_amdgcn_s_sleep(1);
    asm volatile("" ::: "memory");
  }
  __syncthreads();
}

// Persistent fused LSTM: 256 blocks x 1024 threads (16 waves = 4/SIMD).
// Block = (b-tile 16: bt=bid>>5, j-tile 16: jt=bid&31); bid%8 fixes jt%8 ->
// 2.88 MB weights/XCD (L2-resident).
// r18 vs r17: __launch_bounds__(1024, 4) grants a 128-VGPR budget (r17's
// plain (1024) defaulted to 64 -> bh arrays spilled to scratch, FETCH 5x).
// Resident set trimmed to bh1[8]+bh2[8] (64 VGPRs, l1+l2 hi-weights);
// l0 streams hi+lo from L2 as in r16. pre stride 68 kept (r17-proven:
// conflicts 4.27e8 -> 1.26e8).
__global__ __launch_bounds__(1024, 4) void lstm_persist(
    const float* __restrict__ embed,
    const unsigned short* __restrict__ wpk,
    const float* __restrict__ bias,
    float* __restrict__ hsys,
    float* __restrict__ h3f,
    unsigned* __restrict__ bar)
{
  const int bid = blockIdx.x;
  const int shard = bid & 7;
  const int jt = bid & 31;           // j-tile 16
  const int bt = bid >> 5;           // b-tile 16
  const int tid = (int)threadIdx.x;
  const int lane = tid & 63;
  const int w = tid >> 6;            // 0..15
  const int nsub = w & 3, kq = w >> 2;

  __shared__ short als[2][56][520];      // 116480 B, fragment-major + pad
  __shared__ float pre[2][4][16][68];    // 34816 B, stride 68 -> 2-way banks
  __shared__ float sbias[3][64];         // 768 B

  if (tid < 192) {
    const int l = tid >> 6, c = tid & 63;
    const int n = c & 15, g = n >> 2;
    sbias[l][c] = bias[l * 2048 + g * 512 + jt * 16 + (c >> 4) * 4 + (n & 3)];
  }
  // zero h (sys, deterministic per launch)
  unsigned long long* hz = (unsigned long long*)hsys;
  for (int i = bid * 1024 + tid; i < 196608; i += NB * 1024)
    __hip_atomic_store(hz + i, 0ull, __ATOMIC_RELAXED, __HIP_MEMORY_SCOPE_SYSTEM);

  // ---- register-resident B-hi for l1,l2 (64 VGPRs; fits the 128 budget) ----
  const int G = jt * 4 + nsub;
  bf16x8 bh1[8], bh2[8];
  {
    const unsigned short* w1 = wpk + L1B + (size_t)G * 32768 + (size_t)lane * 8;
#pragma unroll
    for (int i = 0; i < 8; ++i)
      bh1[i] = *reinterpret_cast<const bf16x8*>(w1 + (size_t)(kq * 8 + i) * 512);
    const unsigned short* w2 = wpk + L2B + (size_t)G * 32768 + (size_t)lane * 8;
#pragma unroll
    for (int i = 0; i < 8; ++i)
      bh2[i] = *reinterpret_cast<const bf16x8*>(w2 + (size_t)(kq * 8 + i) * 512);
  }

  float c0 = 0.f, c1 = 0.f, c2 = 0.f;   // cell state (bt*16+(tid>>4), jt*16+(tid&15)), tid<256
  unsigned bidx = 1;
  gridbar(bar, bidx++, shard);

  const unsigned long long* hs_u = (const unsigned long long*)hsys;

// l0: both splits streamed from L2 (r16 pattern)
#define MFMA_L0(PL)                                                                      \
  do {                                                                                   \
    const unsigned short* wb = wpk + L0B + (size_t)G * 24576 + (size_t)lane * 8;         \
    f32x4 accE = {0.f,0.f,0.f,0.f}, accO = {0.f,0.f,0.f,0.f};                            \
    _Pragma("unroll")                                                                    \
    for (int i = 0; i < 6; ++i) {                                                        \
      const int kc = kq * 6 + i;                                                         \
      const bf16x8 aH = *reinterpret_cast<const bf16x8*>(&als[0][kc][lane * 8]);         \
      const bf16x8 aL = *reinterpret_cast<const bf16x8*>(&als[1][kc][lane * 8]);         \
      const bf16x8 bH = *reinterpret_cast<const bf16x8*>(wb + (size_t)kc * 512);         \
      const bf16x8 bL = *reinterpret_cast<const bf16x8*>(wb + (size_t)(24 + kc) * 512);  \
      if (i & 1) {                                                                       \
        accO = __builtin_amdgcn_mfma_f32_16x16x32_bf16(aH, bH, accO, 0, 0, 0);           \
        accO = __builtin_amdgcn_mfma_f32_16x16x32_bf16(aL, bH, accO, 0, 0, 0);           \
        accO = __builtin_amdgcn_mfma_f32_16x16x32_bf16(aH, bL, accO, 0, 0, 0);           \
        accO = __builtin_amdgcn_mfma_f32_16x16x32_bf16(aL, bL, accO, 0, 0, 0);           \
      } else {                                                                           \
        accE = __builtin_amdgcn_mfma_f32_16x16x32_bf16(aH, bH, accE, 0, 0, 0);           \
        accE = __builtin_amdgcn_mfma_f32_16x16x32_bf16(aL, bH, accE, 0, 0, 0);           \
        accE = __builtin_amdgcn_mfma_f32_16x16x32_bf16(aH, bL, accE, 0, 0, 0);           \
        accE = __builtin_amdgcn_mfma_f32_16x16x32_bf16(aL, bL, accE, 0, 0, 0);           \
      }                                                                                  \
    }                                                                                    \
    const int prow = (lane >> 4) << 2;                                                   \
    const int pc = lane & 15;                                                            \
    _Pragma("unroll")                                                                    \
    for (int r = 0; r < 4; ++r)                                                          \
      pre[PL][kq][prow + r][nsub * 16 + pc] = accE[r] + accO[r];                         \
  } while (0)

// l1/l2: B-hi from registers, B-lo streamed from L2
#define MFMA_LREG(BH, WBASE, LBASE, PL)                                                  \
  do {                                                                                   \
    const unsigned short* wl_ = wpk + (WBASE) + (size_t)G * 32768 + 16384 +              \
                                (size_t)lane * 8;                                        \
    f32x4 accE = {0.f,0.f,0.f,0.f}, accO = {0.f,0.f,0.f,0.f};                            \
    _Pragma("unroll")                                                                    \
    for (int i = 0; i < 8; ++i) {                                                        \
      const int kc = kq * 8 + i;                                                         \
      const int ch = (LBASE) + kc;                                                       \
      const bf16x8 aH = *reinterpret_cast<const bf16x8*>(&als[0][ch][lane * 8]);         \
      const bf16x8 aL = *reinterpret_cast<const bf16x8*>(&als[1][ch][lane * 8]);         \
      const bf16x8 bH = (BH)[i];                                                         \
      const bf16x8 bL = *reinterpret_cast<const bf16x8*>(wl_ + (size_t)kc * 512);        \
      if (i & 1) {                                                                       \
        accO = __builtin_amdgcn_mfma_f32_16x16x32_bf16(aH, bH, accO, 0, 0, 0);           \
        accO = __builtin_amdgcn_mfma_f32_16x16x32_bf16(aL, bH, accO, 0, 0, 0);           \
        accO = __builtin_amdgcn_mfma_f32_16x16x32_bf16(aH, bL, accO, 0, 0, 0);           \
        accO = __builtin_amdgcn_mfma_f32_16x16x32_bf16(aL, bL, accO, 0, 0, 0);           \
      } else {                                                                           \
        accE = __builtin_amdgcn_mfma_f32_16x16x32_bf16(aH, bH, accE, 0, 0, 0);           \
        accE = __builtin_amdgcn_mfma_f32_16x16x32_bf16(aL, bH, accE, 0, 0, 0);           \
        accE = __builtin_amdgcn_mfma_f32_16x16x32_bf16(aH, bL, accE, 0, 0, 0);           \
        accE = __builtin_amdgcn_mfma_f32_16x16x32_bf16(aL, bL, accE, 0, 0, 0);           \
      }                                                                                  \
    }                                                                                    \
    const int prow = (lane >> 4) << 2;                                                   \
    const int pc = lane & 15;                                                            \
    _Pragma("unroll")                                                                    \
    for (int r = 0; r < 4; ++r)                                                          \
      pre[PL][kq][prow + r][nsub * 16 + pc] = accE[r] + accO[r];                         \
  } while (0)

  // cell update for one layer (tid<256): b=tid>>4, jl=tid&15
  auto cell_layer = [&](int l, int pl, int wp, int t, float& c) {
    const int b = tid >> 4, jl = tid & 15;
    float gv[4];
#pragma unroll
    for (int gi = 0; gi < 4; ++gi) {
      const int cc = (jl >> 2) * 16 + gi * 4 + (jl & 3);
      gv[gi] = sbias[l][cc] + pre[pl][0][b][cc] + pre[pl][1][b][cc]
             + pre[pl][2][b][cc] + pre[pl][3][b][cc];
    }
    const float ig = sigm(gv[0]), fg = sigm(gv[1]), gg = tanhf(gv[2]), og = sigm(gv[3]);
    c = fg * c + ig * gg;
    const float hv = og * tanhf(c);
    __hip_atomic_store((unsigned*)hsys +
        ((size_t)(l * 2 + wp) * 65536 + (size_t)(bt * 16 + b) * 512 + jt * 16 + jl),
        __builtin_bit_cast(unsigned, hv), __ATOMIC_RELAXED, __HIP_MEMORY_SCOPE_SYSTEM);
    if (l == 2 && t == 1022)
      h3f[(size_t)(bt * 16 + b) * 512 + jt * 16 + jl] = hv;
  };

  for (int p = 0; p <= 1024; ++p) {
    const int rp = (p + 1) & 1, wp = p & 1;
    const bool a0 = (p <= 1022), a1 = (p >= 1) && (p <= 1023), a2 = (p >= 2);

    // ---- deduped stage, ch-major: sub = consuming lane; writes contiguous ----
    for (int u = tid; u < 3584; u += 1024) {
      float xs[8];
      int ch, sub;
      if (u < 512) {                       // embed: chunks 0-7
        if (p > 1022) continue;
        ch = u >> 6; sub = u & 63;
        const int row = sub & 15, kg = sub >> 4;
        const int k0 = ch * 32 + kg * 8;
        const float* s = embed + ((size_t)(bt * 16 + row) * Tn + p) * INn + k0;
        const f32x4 x0 = __builtin_nontemporal_load(reinterpret_cast<const f32x4*>(s));
        const f32x4 x1 = __builtin_nontemporal_load(reinterpret_cast<const f32x4*>(s) + 1);
        xs[0]=x0.x; xs[1]=x0.y; xs[2]=x0.z; xs[3]=x0.w;
        xs[4]=x1.x; xs[5]=x1.y; xs[6]=x1.z; xs[7]=x1.w;
      } else {                             // h_li: chunks 8..55
        const int v = u - 512;
        const int chh = v >> 6;            // 0..47
        ch = 8 + chh; sub = v & 63;
        const int li = chh >> 4;           // 0..2
        const int row = sub & 15, kg = sub >> 4;
        const int kcol = (chh & 15) * 32 + kg * 8;   // within li's 512
        const unsigned long long* sp = hs_u +
            ((size_t)(li * 2 + rp) * 32768 + (size_t)(bt * 16 + row) * 256 + (kcol >> 1));
#pragma unroll
        for (int q = 0; q < 4; ++q) {
          unsigned long long vv = __hip_atomic_load(sp + q, __ATOMIC_RELAXED, __HIP_MEMORY_SCOPE_SYSTEM);
          xs[2*q]   = __builtin_bit_cast(float, (unsigned)(vv & 0xffffffffu));
          xs[2*q+1] = __builtin_bit_cast(float, (unsigned)(vv >> 32));
        }
      }
      bf16x8 vh, vl;
#pragma unroll
      for (int e = 0; e < 8; ++e) {
        unsigned short h1 = bf_hi(xs[e]);
        vh[e] = (short)h1;
        vl[e] = (short)bf_hi(xs[e] - bf_f(h1));
      }
      *reinterpret_cast<bf16x8*>(&als[0][ch][sub * 8]) = vh;
      *reinterpret_cast<bf16x8*>(&als[1][ch][sub * 8]) = vl;
    }
    __syncthreads();

    // ---- mfma l0 -> pre[0], l1 -> pre[1] ----
    if (a0) MFMA_L0(0);
    if (a1) MFMA_LREG(bh1, L1B, 8, 1);
    __syncthreads();
    if (tid < 256) {
      if (a0) cell_layer(0, 0, wp, p, c0);
      if (a1) cell_layer(1, 1, wp, p - 1, c1);
    }
    __syncthreads();

    // ---- mfma l2 -> pre[0] (cells above already consumed pre[0]) ----
    if (a2) MFMA_LREG(bh2, L2B, 24, 0);
    __syncthreads();
    if (tid < 256 && a2) cell_layer(2, 0, wp, p - 2, c2);

    gridbar(bar, bidx++, shard);
  }
}

// FC epilogue: out2[b][o] = h3_final[b,:] . fc_w[o,:] + fc_b[o]
__global__ void fc_kernel(const float* __restrict__ h3f, const float* __restrict__ fcw,
                          const float* __restrict__ fcb, float* __restrict__ out) {
  const int gid = blockIdx.x * 256 + (int)threadIdx.x;
  if (gid >= Bn * INn) return;
  const int b = gid >> 8, o = gid & 255;
  const float* hr = h3f + (size_t)b * Hn;
  const float* wr = fcw + (size_t)o * Hn;
  float acc = fcb[o];
#pragma unroll 4
  for (int k = 0; k < Hn; k += 4) {
    const float4 hv = *reinterpret_cast<const float4*>(hr + k);
    const float4 wv = *reinterpret_cast<const float4*>(wr + k);
    acc = fmaf(hv.x, wv.x, acc); acc = fmaf(hv.y, wv.y, acc);
    acc = fmaf(hv.z, wv.z, acc); acc = fmaf(hv.w, wv.w, acc);
  }
  out[(size_t)Bn * Tn * INn + gid] = acc;
}

extern "C" void kernel_launch(void* const* d_in, const int* in_sizes, int n_in,
                              void* d_out, int out_size, void* d_ws, size_t ws_size,
                              hipStream_t stream) {
  const float* embed = (const float*)d_in[0];
  const float* wih1  = (const float*)d_in[1];
  const float* whh1  = (const float*)d_in[2];
  const float* bih1  = (const float*)d_in[3];
  const float* bhh1  = (const float*)d_in[4];
  const float* wih2  = (const float*)d_in[5];
  const float* whh2  = (const float*)d_in[6];
  const float* bih2  = (const float*)d_in[7];
  const float* bhh2  = (const float*)d_in[8];
  const float* wih3  = (const float*)d_in[9];
  const float* whh3  = (const float*)d_in[10];
  const float* bih3  = (const float*)d_in[11];
  const float* bhh3  = (const float*)d_in[12];
  const float* fcw   = (const float*)d_in[13];
  const float* fcb   = (const float*)d_in[14];
  float* outp = (float*)d_out;

  char* ws = (char*)d_ws;
  unsigned short* wpk = (unsigned short*)(ws + WPK_OFF);
  float* bias         = (float*)(ws + BIAS_OFF);
  float* hsys         = (float*)(ws + H_OFF);
  float* h3f          = (float*)(ws + H3F_OFF);
  unsigned* bar       = (unsigned*)(ws + BAR_OFF);

  // Output 0: embed passthrough (128 MB d2d)
  hipMemcpyAsync(d_out, d_in[0], (size_t)Bn * Tn * INn * sizeof(float),
                 hipMemcpyDeviceToDevice, stream);
  hipMemsetAsync(bar, 0, 8192, stream);

  pack_weights<<<2816, 256, 0, stream>>>(wih1, whh1, wih2, whh2, wih3, whh3, wpk);
  pack_bias<<<24, 256, 0, stream>>>(bih1, bhh1, bih2, bhh2, bih3, bhh3, bias);

  void* args[] = { (void*)&embed, (void*)&wpk, (void*)&bias,
                   (void*)&hsys, (void*)&h3f, (void*)&bar };
  dim3 grid(NB), block(1024);
  hipLaunchCooperativeKernel((const void*)lstm_persist, grid, block, args, 0, stream);

  fc_kernel<<<128, 256, 0, stream>>>(h3f, fcw, fcb, outp);
}

// Round 19
// 16276.291 us; speedup vs baseline: 1.6061x; 1.5416x over previous
//
#include <hip/hip_runtime.h>

#define Bn 128
#define Tn 1024
#define INn 256
#define Hn 512
#define NB 256   // persistent blocks (1 per CU), 1024 threads each

typedef short bf16x8 __attribute__((ext_vector_type(8)));
typedef float f32x4 __attribute__((ext_vector_type(4)));
typedef int   i32x4 __attribute__((ext_vector_type(4)));

// ---- ws layout (bytes) ----
#define WPK_OFF  0u           // bf16 packed weights 23068672 B
#define BIAS_OFF 23068672u    // f32[3][2048]
#define H_OFF    23093248u    // f32 h[3][2][128][512], MALL/sys-coherent
#define H3F_OFF  24666112u    // f32[128][512]
#define BAR_OFF  24928256u    // 8KB barrier

// packed-weight bases (bf16 elems); per-G slab: l0=24576, l1/l2=32768 elems
#define L0B 0u
#define L1B 3145728u
#define L2B 7340032u

__device__ __forceinline__ float sigm(float x) { return 1.0f / (1.0f + __expf(-x)); }
__device__ __forceinline__ unsigned short bf_hi(float x) {
  unsigned u = __builtin_bit_cast(unsigned, x);
  return (unsigned short)(u >> 16);
}
__device__ __forceinline__ float bf_f(unsigned short h) {
  unsigned u = ((unsigned)h) << 16;
  return __builtin_bit_cast(float, u);
}

// 16B system-coherent load (sc0 sc1 = bypass L1/L2, served at MALL) --
// same coherence bits the compiler emits for SYSTEM-scope relaxed atomics
// (r9-proven), but 16B wide. waitvm passes values through "+v" so the
// compiler cannot hoist uses above the waitcnt (rule #18 safe).
__device__ __forceinline__ i32x4 ld16_sc(const void* p) {
  i32x4 r;
  asm volatile("global_load_dwordx4 %0, %1, off sc0 sc1" : "=&v"(r) : "v"(p));
  return r;
}
__device__ __forceinline__ void waitvm2(i32x4& a, i32x4& b) {
  asm volatile("s_waitcnt vmcnt(0)" : "+v"(a), "+v"(b));
}

// Pack fp32 weights -> per-(layer, 16-col group G) slabs in MFMA fragment
// order (r13-proven layout). slab = [NCH][64][8] hi then same-size lo.
// col n = lane&15 -> gate g=n>>2, jl=n&3 -> row r = g*512 + G*4 + jl;
// k0 = kc*32 + (lane>>4)*8 over concat [x ; h].
__global__ void pack_weights(const float* __restrict__ wih1, const float* __restrict__ whh1,
                             const float* __restrict__ wih2, const float* __restrict__ whh2,
                             const float* __restrict__ wih3, const float* __restrict__ whh3,
                             unsigned short* __restrict__ wpk) {
  int gid = blockIdx.x * 256 + threadIdx.x;
  int rem, NCH, kih; size_t base, slab; const float *wih, *whh;
  if (gid < 196608)      { rem = gid;          base = L0B; slab = 24576; NCH = 24; kih = 256; wih = wih1; whh = whh1; }
  else if (gid < 458752) { rem = gid - 196608; base = L1B; slab = 32768; NCH = 32; kih = 512; wih = wih2; whh = whh2; }
  else if (gid < 720896) { rem = gid - 458752; base = L2B; slab = 32768; NCH = 32; kih = 512; wih = wih3; whh = whh3; }
  else return;
  const int lane = rem & 63; rem >>= 6;
  const int kc = rem % NCH; rem /= NCH;
  const int G = rem;                      // 0..127
  const int n = lane & 15;
  const int g = n >> 2, jl = n & 3;
  const int r = g * 512 + G * 4 + jl;
  const int k0 = kc * 32 + (lane >> 4) * 8;
  const float* src = (k0 < kih) ? (wih + (size_t)r * kih + k0)
                                : (whh + (size_t)r * 512 + (k0 - kih));
  const size_t dhi = base + (size_t)G * slab + (size_t)kc * 512 + lane * 8;
  const size_t dlo = dhi + (size_t)NCH * 512;
#pragma unroll
  for (int e = 0; e < 8; ++e) {
    float w = src[e];
    unsigned short h = bf_hi(w);
    wpk[dhi + e] = h;
    wpk[dlo + e] = bf_hi(w - bf_f(h));
  }
}

__global__ void pack_bias(const float* __restrict__ bi1, const float* __restrict__ bh1,
                          const float* __restrict__ bi2, const float* __restrict__ bh2,
                          const float* __restrict__ bi3, const float* __restrict__ bh3,
                          float* __restrict__ bias) {
  int gid = blockIdx.x * 256 + threadIdx.x;
  if (gid >= 6144) return;
  int l = gid >> 11, r = gid & 2047;
  const float* bi = (l == 0) ? bi1 : (l == 1) ? bi2 : bi3;
  const float* bh = (l == 0) ? bh1 : (l == 1) ? bh2 : bh3;
  bias[gid] = bi[r] + bh[r];
}

// Grid barrier, ALL RELAXED (r9-proven). Counter-sharding by bid&7.
__device__ __forceinline__ void gridbar(unsigned* bar, unsigned idx, int shard) {
  __syncthreads();
  if (threadIdx.x == 0) {
    asm volatile("" ::: "memory");
    unsigned o = __hip_atomic_fetch_add(bar + shard * 32, 1u, __ATOMIC_RELAXED, __HIP_MEMORY_SCOPE_AGENT);
    if (o == idx * 32u - 1u) {
      unsigned r = __hip_atomic_fetch_add(bar + 256, 1u, __ATOMIC_RELAXED, __HIP_MEMORY_SCOPE_AGENT);
      if (r == idx * 8u - 1u)
        __hip_atomic_store(bar + 288, idx, __ATOMIC_RELAXED, __HIP_MEMORY_SCOPE_AGENT);
    }
    while (__hip_atomic_load(bar + 288, __ATOMIC_RELAXED, __HIP_MEMORY_SCOPE_AGENT) < idx)
      __builtin_amdgcn_s_sleep(1);
    asm volatile("" ::: "memory");
  }
  __syncthreads();
}

// Persistent fused LSTM: 256 blocks x 1024 threads (16 waves = 4/SIMD).
// Block = (b-tile 16: bt=bid>>5, j-tile 16: jt=bid&31); bid%8 fixes jt%8 ->
// 2.88 MB weights/XCD (L2-resident). r16 structure (VGPR 64, no spill).
// r19 vs r16: (1) 3-term split product HH+LH+HL (drops aL*bL ~2^-16 rel;
// r2-proven absmax 2.4e-4) -> 25% fewer MFMAs; (2) stage h-loads are 16B
// system-coherent asm loads (half the VMEM instructions of 2x8B atomics);
// (3) pre stride 68 kept (r17-proven: conflicts 4.3e8 -> 1.3e8).
__global__ __launch_bounds__(1024) void lstm_persist(
    const float* __restrict__ embed,
    const unsigned short* __restrict__ wpk,
    const float* __restrict__ bias,
    float* __restrict__ hsys,
    float* __restrict__ h3f,
    unsigned* __restrict__ bar)
{
  const int bid = blockIdx.x;
  const int shard = bid & 7;
  const int jt = bid & 31;           // j-tile 16
  const int bt = bid >> 5;           // b-tile 16
  const int tid = (int)threadIdx.x;
  const int lane = tid & 63;
  const int w = tid >> 6;            // 0..15
  const int nsub = w & 3, kq = w >> 2;

  __shared__ short als[2][56][520];      // 116480 B, fragment-major + pad
  __shared__ float pre[2][4][16][68];    // 34816 B, stride 68 -> 2-way banks
  __shared__ float sbias[3][64];         // 768 B

  if (tid < 192) {
    const int l = tid >> 6, c = tid & 63;
    const int n = c & 15, g = n >> 2;
    sbias[l][c] = bias[l * 2048 + g * 512 + jt * 16 + (c >> 4) * 4 + (n & 3)];
  }
  // zero h (sys, deterministic per launch)
  unsigned long long* hz = (unsigned long long*)hsys;
  for (int i = bid * 1024 + tid; i < 196608; i += NB * 1024)
    __hip_atomic_store(hz + i, 0ull, __ATOMIC_RELAXED, __HIP_MEMORY_SCOPE_SYSTEM);

  float c0 = 0.f, c1 = 0.f, c2 = 0.f;   // cell state (bt*16+(tid>>4), jt*16+(tid&15)), tid<256
  unsigned bidx = 1;
  gridbar(bar, bidx++, shard);

  const unsigned long long* hs_u = (const unsigned long long*)hsys;
  const int G = jt * 4 + nsub;

  // per-layer MFMA pass: A from fragment-major LDS, B from L2 weights.
  // 3-term split: aH*bH + aL*bH + aH*bL (LL term ~2^-16 rel, dropped).
  auto mfma_layer = [&](int NCH, int q4, size_t wbase, size_t slab, int lbase, int pl) {
    const unsigned short* wb = wpk + wbase + (size_t)G * slab + (size_t)lane * 8;
    f32x4 accE = {0.f,0.f,0.f,0.f}, accO = {0.f,0.f,0.f,0.f};
#pragma unroll
    for (int i = 0; i < 8; ++i) {
      if (i >= q4) break;                // compile-time per call site
      const int kc = kq * q4 + i;
      const int ch = lbase + kc;
      const bf16x8 aH = *reinterpret_cast<const bf16x8*>(&als[0][ch][lane * 8]);
      const bf16x8 aL = *reinterpret_cast<const bf16x8*>(&als[1][ch][lane * 8]);
      const bf16x8 bH = *reinterpret_cast<const bf16x8*>(wb + (size_t)kc * 512);
      const bf16x8 bL = *reinterpret_cast<const bf16x8*>(wb + (size_t)(NCH + kc) * 512);
      if (i & 1) {
        accO = __builtin_amdgcn_mfma_f32_16x16x32_bf16(aH, bH, accO, 0, 0, 0);
        accO = __builtin_amdgcn_mfma_f32_16x16x32_bf16(aL, bH, accO, 0, 0, 0);
        accO = __builtin_amdgcn_mfma_f32_16x16x32_bf16(aH, bL, accO, 0, 0, 0);
      } else {
        accE = __builtin_amdgcn_mfma_f32_16x16x32_bf16(aH, bH, accE, 0, 0, 0);
        accE = __builtin_amdgcn_mfma_f32_16x16x32_bf16(aL, bH, accE, 0, 0, 0);
        accE = __builtin_amdgcn_mfma_f32_16x16x32_bf16(aH, bL, accE, 0, 0, 0);
      }
    }
    const int prow = (lane >> 4) << 2;
    const int pc = lane & 15;
#pragma unroll
    for (int r = 0; r < 4; ++r)
      pre[pl][kq][prow + r][nsub * 16 + pc] = accE[r] + accO[r];
  };

  // cell update for one layer (tid<256): b=tid>>4, jl=tid&15
  auto cell_layer = [&](int l, int pl, int wp, int t, float& c) {
    const int b = tid >> 4, jl = tid & 15;
    float gv[4];
#pragma unroll
    for (int gi = 0; gi < 4; ++gi) {
      const int cc = (jl >> 2) * 16 + gi * 4 + (jl & 3);
      gv[gi] = sbias[l][cc] + pre[pl][0][b][cc] + pre[pl][1][b][cc]
             + pre[pl][2][b][cc] + pre[pl][3][b][cc];
    }
    const float ig = sigm(gv[0]), fg = sigm(gv[1]), gg = tanhf(gv[2]), og = sigm(gv[3]);
    c = fg * c + ig * gg;
    const float hv = og * tanhf(c);
    __hip_atomic_store((unsigned*)hsys +
        ((size_t)(l * 2 + wp) * 65536 + (size_t)(bt * 16 + b) * 512 + jt * 16 + jl),
        __builtin_bit_cast(unsigned, hv), __ATOMIC_RELAXED, __HIP_MEMORY_SCOPE_SYSTEM);
    if (l == 2 && t == 1022)
      h3f[(size_t)(bt * 16 + b) * 512 + jt * 16 + jl] = hv;
  };

  for (int p = 0; p <= 1024; ++p) {
    const int rp = (p + 1) & 1, wp = p & 1;
    const bool a0 = (p <= 1022), a1 = (p >= 1) && (p <= 1023), a2 = (p >= 2);

    // ---- deduped stage, ch-major: sub = consuming lane; writes contiguous ----
    for (int u = tid; u < 3584; u += 1024) {
      float xs[8];
      int ch, sub;
      if (u < 512) {                       // embed: chunks 0-7 (plain nt loads)
        if (p > 1022) continue;
        ch = u >> 6; sub = u & 63;
        const int row = sub & 15, kg = sub >> 4;
        const int k0 = ch * 32 + kg * 8;
        const float* s = embed + ((size_t)(bt * 16 + row) * Tn + p) * INn + k0;
        const f32x4 x0 = __builtin_nontemporal_load(reinterpret_cast<const f32x4*>(s));
        const f32x4 x1 = __builtin_nontemporal_load(reinterpret_cast<const f32x4*>(s) + 1);
        xs[0]=x0.x; xs[1]=x0.y; xs[2]=x0.z; xs[3]=x0.w;
        xs[4]=x1.x; xs[5]=x1.y; xs[6]=x1.z; xs[7]=x1.w;
      } else {                             // h_li: chunks 8..55, 16B sc loads
        const int v = u - 512;
        const int chh = v >> 6;            // 0..47
        ch = 8 + chh; sub = v & 63;
        const int li = chh >> 4;           // 0..2
        const int row = sub & 15, kg = sub >> 4;
        const int kcol = (chh & 15) * 32 + kg * 8;   // within li's 512
        const unsigned long long* sp = hs_u +
            ((size_t)(li * 2 + rp) * 32768 + (size_t)(bt * 16 + row) * 256 + (kcol >> 1));
        i32x4 lo = ld16_sc(sp);
        i32x4 hi = ld16_sc(sp + 2);
        waitvm2(lo, hi);
#pragma unroll
        for (int q = 0; q < 4; ++q) {
          xs[q]     = __builtin_bit_cast(float, lo[q]);
          xs[4 + q] = __builtin_bit_cast(float, hi[q]);
        }
      }
      bf16x8 vh, vl;
#pragma unroll
      for (int e = 0; e < 8; ++e) {
        unsigned short h1 = bf_hi(xs[e]);
        vh[e] = (short)h1;
        vl[e] = (short)bf_hi(xs[e] - bf_f(h1));
      }
      *reinterpret_cast<bf16x8*>(&als[0][ch][sub * 8]) = vh;
      *reinterpret_cast<bf16x8*>(&als[1][ch][sub * 8]) = vl;
    }
    __syncthreads();

    // ---- mfma l0 -> pre[0], l1 -> pre[1] ----
    if (a0) mfma_layer(24, 6, L0B, 24576, 0, 0);
    if (a1) mfma_layer(32, 8, L1B, 32768, 8, 1);
    __syncthreads();
    if (tid < 256) {
      if (a0) cell_layer(0, 0, wp, p, c0);
      if (a1) cell_layer(1, 1, wp, p - 1, c1);
    }
    __syncthreads();

    // ---- mfma l2 -> pre[0] (cells above already consumed pre[0]) ----
    if (a2) mfma_layer(32, 8, L2B, 32768, 24, 0);
    __syncthreads();
    if (tid < 256 && a2) cell_layer(2, 0, wp, p - 2, c2);

    gridbar(bar, bidx++, shard);
  }
}

// FC epilogue: out2[b][o] = h3_final[b,:] . fc_w[o,:] + fc_b[o]
__global__ void fc_kernel(const float* __restrict__ h3f, const float* __restrict__ fcw,
                          const float* __restrict__ fcb, float* __restrict__ out) {
  const int gid = blockIdx.x * 256 + (int)threadIdx.x;
  if (gid >= Bn * INn) return;
  const int b = gid >> 8, o = gid & 255;
  const float* hr = h3f + (size_t)b * Hn;
  const float* wr = fcw + (size_t)o * Hn;
  float acc = fcb[o];
#pragma unroll 4
  for (int k = 0; k < Hn; k += 4) {
    const float4 hv = *reinterpret_cast<const float4*>(hr + k);
    const float4 wv = *reinterpret_cast<const float4*>(wr + k);
    acc = fmaf(hv.x, wv.x, acc); acc = fmaf(hv.y, wv.y, acc);
    acc = fmaf(hv.z, wv.z, acc); acc = fmaf(hv.w, wv.w, acc);
  }
  out[(size_t)Bn * Tn * INn + gid] = acc;
}

extern "C" void kernel_launch(void* const* d_in, const int* in_sizes, int n_in,
                              void* d_out, int out_size, void* d_ws, size_t ws_size,
                              hipStream_t stream) {
  const float* embed = (const float*)d_in[0];
  const float* wih1  = (const float*)d_in[1];
  const float* whh1  = (const float*)d_in[2];
  const float* bih1  = (const float*)d_in[3];
  const float* bhh1  = (const float*)d_in[4];
  const float* wih2  = (const float*)d_in[5];
  const float* whh2  = (const float*)d_in[6];
  const float* bih2  = (const float*)d_in[7];
  const float* bhh2  = (const float*)d_in[8];
  const float* wih3  = (const float*)d_in[9];
  const float* whh3  = (const float*)d_in[10];
  const float* bih3  = (const float*)d_in[11];
  const float* bhh3  = (const float*)d_in[12];
  const float* fcw   = (const float*)d_in[13];
  const float* fcb   = (const float*)d_in[14];
  float* outp = (float*)d_out;

  char* ws = (char*)d_ws;
  unsigned short* wpk = (unsigned short*)(ws + WPK_OFF);
  float* bias         = (float*)(ws + BIAS_OFF);
  float* hsys         = (float*)(ws + H_OFF);
  float* h3f          = (float*)(ws + H3F_OFF);
  unsigned* bar       = (unsigned*)(ws + BAR_OFF);

  // Output 0: embed passthrough (128 MB d2d)
  hipMemcpyAsync(d_out, d_in[0], (size_t)Bn * Tn * INn * sizeof(float),
                 hipMemcpyDeviceToDevice, stream);
  hipMemsetAsync(bar, 0, 8192, stream);

  pack_weights<<<2816, 256, 0, stream>>>(wih1, whh1, wih2, whh2, wih3, whh3, wpk);
  pack_bias<<<24, 256, 0, stream>>>(bih1, bhh1, bih2, bhh2, bih3, bhh3, bias);

  void* args[] = { (void*)&embed, (void*)&wpk, (void*)&bias,
                   (void*)&hsys, (void*)&h3f, (void*)&bar };
  dim3 grid(NB), block(1024);
  hipLaunchCooperativeKernel((const void*)lstm_persist, grid, block, args, 0, stream);

  fc_kernel<<<128, 256, 0, stream>>>(h3f, fcw, fcb, outp);
}